// Round 5
// baseline (925.380 us; speedup 1.0000x reference)
//
#include <hip/hip_runtime.h>
#include <hip/hip_bf16.h>
#include <math.h>

// LineRWKVBlock: y = (x + sigmoid(x@Wr) * scan(x@Wv)) ; y += y@Wc
// B=16, W=2048, D=1024, decay=0.99.
//
// R7: R6 + the missing piece of the m201 template: the ONE-PHASE REGISTER
// PIPELINE. R6's phases read operands for their OWN MFMA -> all-wave LDS burst
// (96 KiB @ ~85 B/cyc ~ 1150 cyc) serialized with the 512-cyc MFMA cluster
// (wall 6370 cyc/K-tile, MfmaUtil 34%). R7: each phase's ds_reads feed the
// NEXT phase's MFMA; counted (compiler-auto) lgkm waits keep this phase's
// reads outstanding during MFMA. Quadrant rotation (L,01)(L,23)(H,23)(H,01),
// reads p0:8 p1:4 p2:0 p3:12 p4:8 p5:4 p6:0 p7:12 (24/wave/K-tile, minimal).
// Stages packed into zero-read phases (p2:R.B, p3:R.A, p6:S.B, p7:S.A);
// vmcnt(4) at p2/p6 end retires exactly the tile read next phase (3-phase
// HBM margin). Swizzles (LDS both-sides + XCD) unchanged, conflicts = 0.
//
// ws: WT 6 MiB | Xb 64 | V/y_tmp 64 | R 64 | sl 1 | s_in 1  = 200 MiB

#define MROWS 32768           // B*W
#define NCHUNK 16
#define CHUNKL 128
#define DECAY_F 0.99f
#define OM_F 0.01f

typedef __attribute__((ext_vector_type(8))) short short8;   // 8 bf16 (4 VGPRs)
typedef __attribute__((ext_vector_type(4))) float floatx4;

using bf16 = __hip_bfloat16;
using bf162 = __hip_bfloat162;

// async global->LDS, 16B per lane; lds base wave-uniform, HW scatters lane i at
// base + i*16.
__device__ __forceinline__ void async_copy16(const void* g, void* l) {
  __builtin_amdgcn_global_load_lds(
      (const __attribute__((address_space(1))) unsigned int*)g,
      (__attribute__((address_space(3))) unsigned int*)l, 16, 0, 0);
}

#define S_BARRIER() asm volatile("s_barrier" ::: "memory")
#define SCHED0() __builtin_amdgcn_sched_barrier(0)
#define VMCNT(N)                                                               \
  do {                                                                         \
    asm volatile("s_waitcnt vmcnt(" #N ")" ::: "memory");                      \
    __builtin_amdgcn_sched_barrier(0);                                         \
  } while (0)

// ---------------- kernel 1: x fp32 -> bf16 ----------------
__global__ void prep_x(const float* __restrict__ X, bf16* __restrict__ Xb) {
  const int idx = blockIdx.x * 256 + threadIdx.x;   // 8388608 float4-groups
  const float4 v = ((const float4*)X)[idx];
  union { ushort4 u; bf16 h[4]; } pk;
  pk.h[0] = __float2bfloat16(v.x);
  pk.h[1] = __float2bfloat16(v.y);
  pk.h[2] = __float2bfloat16(v.z);
  pk.h[3] = __float2bfloat16(v.w);
  ((ushort4*)Xb)[idx] = pk.u;
}

// ---------------- kernel 2: weight transpose + bf16 cast ----------------
// WT rows 0..1023 = Wv^T, 1024..2047 = Wr^T, 2048..3071 = Wc^T ; WT[n][k]
__global__ void prep_weights(const float* __restrict__ Wv,
                             const float* __restrict__ Wr,
                             const float* __restrict__ Wc,
                             bf16* __restrict__ WT) {
  __shared__ float tile[32][33];
  const int bk = blockIdx.x * 32;   // k block
  const int bn = blockIdx.y * 32;   // global n block (0..3071)
  const float* src;
  int nbase = bn;
  if (bn < 1024)      { src = Wv; }
  else if (bn < 2048) { src = Wr; nbase = bn - 1024; }
  else                { src = Wc; nbase = bn - 2048; }
  const int tx = threadIdx.x;       // 32
  const int ty = threadIdx.y;       // 8
  #pragma unroll
  for (int i = ty; i < 32; i += 8)
    tile[i][tx] = src[(size_t)(bk + i) * 1024 + nbase + tx];  // tile[k][n]
  __syncthreads();
  #pragma unroll
  for (int i = ty; i < 32; i += 8)
    WT[(size_t)(bn + i) * 1024 + bk + tx] = __float2bfloat16(tile[tx][i]);
}

// ---------------- kernels 3/7: 256^2 BK=64 8-phase pipelined GEMM ----------
// MODE 0: v/r GEMM  -> Vout bf16 (nt<4), Rout = sigmoid (nt>=4); N=2048
// MODE 1: mix GEMM  -> Fout fp32 = bf16(A)[o] + acc ; N=1024
//
// Dynamic LDS 128 KiB: buf0 { A0@0 | A1@16384 | B0@32768 | B1@49152 },
// buf1 @ +65536. Region = [128 rows][64 bf16] = 16 KiB; rows 128 B,
// swizzle slot' = slot ^ (row&7) on 16B slots (both-sides).

// 16 MFMA quadrant: acc[MB..MB+3][NB..NB+1], both k-halves
#define QMFMA(FA, FB, MB, NB)                                                  \
  __builtin_amdgcn_s_setprio(1);                                               \
  _Pragma("unroll")                                                            \
  for (int mfi = 0; mfi < 4; ++mfi)                                            \
    _Pragma("unroll")                                                          \
    for (int nfi = 0; nfi < 2; ++nfi)                                          \
      acc[(MB) + mfi][(NB) + nfi] = __builtin_amdgcn_mfma_f32_16x16x32_bf16(   \
          FA[mfi][0], FB[nfi][0], acc[(MB) + mfi][(NB) + nfi], 0, 0, 0);       \
  _Pragma("unroll")                                                            \
  for (int mfi = 0; mfi < 4; ++mfi)                                            \
    _Pragma("unroll")                                                          \
    for (int nfi = 0; nfi < 2; ++nfi)                                          \
      acc[(MB) + mfi][(NB) + nfi] = __builtin_amdgcn_mfma_f32_16x16x32_bf16(   \
          FA[mfi][1], FB[nfi][1], acc[(MB) + mfi][(NB) + nfi], 0, 0, 0);       \
  __builtin_amdgcn_s_setprio(0);

#define RD_FA4(DST, PTR)                                                       \
  _Pragma("unroll")                                                            \
  for (int f = 0; f < 4; ++f) {                                                \
    DST[f][0] = *(const short8*)((PTR) + f * 2048 + lk0);                      \
    DST[f][1] = *(const short8*)((PTR) + f * 2048 + lk1);                      \
  }
#define RD_FA2(DST, D0, MFB, PTR)                                              \
  DST[D0][0] = *(const short8*)((PTR) + (MFB) * 2048 + lk0);                   \
  DST[D0][1] = *(const short8*)((PTR) + (MFB) * 2048 + lk1);                   \
  DST[(D0) + 1][0] = *(const short8*)((PTR) + ((MFB) + 1) * 2048 + lk0);       \
  DST[(D0) + 1][1] = *(const short8*)((PTR) + ((MFB) + 1) * 2048 + lk1);
#define RD_FB2(DST, NOFF, PTR)                                                 \
  DST[0][0] = *(const short8*)((PTR) + (NOFF) + lk0);                          \
  DST[0][1] = *(const short8*)((PTR) + (NOFF) + lk1);                          \
  DST[1][0] = *(const short8*)((PTR) + (NOFF) + 2048 + lk0);                   \
  DST[1][1] = *(const short8*)((PTR) + (NOFF) + 2048 + lk1);

// stage one 16 KiB region (128 rows x 128 B) = 2 gload_lds of 8 KiB
#define STAGE(GP, LOFF)                                                        \
  do {                                                                         \
    async_copy16((GP), lds + (LOFF) + wb);                                     \
    async_copy16((GP) + (size_t)64 * 2048, lds + (LOFF) + 8192 + wb);          \
  } while (0)

template <int MODE>
__global__ __launch_bounds__(512, 2) void gemm8(const bf16* __restrict__ Ab,
                                                const bf16* __restrict__ Bw,
                                                bf16* __restrict__ Vout,
                                                bf16* __restrict__ Rout,
                                                float* __restrict__ Fout) {
  extern __shared__ char lds[];
  constexpr int NTN = (MODE == 0) ? 8 : 4;

  // bijective XCD-chunk swizzle (nwg % 8 == 0)
  const int nwg = gridDim.x;
  const int id = blockIdx.x;
  const int wg = (id & 7) * (nwg >> 3) + (id >> 3);
  const int mt = wg / NTN, nt = wg % NTN;
  const int m0 = mt * 256, n0 = nt * 256;

  const int t = threadIdx.x;
  const int l = t & 63, w = t >> 6;          // 8 waves
  const int wm = w >> 2, wn = w & 3;         // 2 (M) x 4 (N) wave grid
  const int wb = w * 1024;                   // wave's slice per gload_lds

  // ---- staging: LDS dest linear; global source inverse-swizzled.
  const int sgrow = w * 8 + (l >> 3);
  const int sgcol = ((l & 7) ^ ((l >> 3) & 7)) * 16;
  const char* gA0 = (const char*)Ab + (size_t)(m0 + sgrow) * 2048 + sgcol;
  const char* gA1 = gA0 + (size_t)128 * 2048;
  const char* gB0 = (const char*)Bw + (size_t)(n0 + sgrow) * 2048 + sgcol;
  const char* gB1 = gB0 + (size_t)128 * 2048;

  // ---- read-side: frag (row, kslot = ks*4+qd) at row*128 + (kslot^(row&7))*16
  const int ll = l & 15, qd = l >> 4;
  const int arow = ll * 128;
  const int lk0 = ((qd ^ (ll & 7)) << 4);
  const int lk1 = (((4 | qd) ^ (ll & 7)) << 4);
  const char* pAP = lds + wm * 16384 + arow;                              // buf0 A
  const char* pBP = lds + 32768 + (wn >> 1) * 16384 + (wn & 1) * 8192 + arow;
  const char* pAQ = pAP + 65536;                                          // buf1
  const char* pBQ = pBP + 65536;

  floatx4 acc[8][4];
  #pragma unroll
  for (int i = 0; i < 8; ++i)
    #pragma unroll
    for (int j = 0; j < 4; ++j) acc[i][j] = (floatx4){0.f, 0.f, 0.f, 0.f};

  short8 faL[4][2], faH[4][2], fbA[2][2], fbB[2][2];

  // ---- prologue: T0 -> buf0, T1 -> buf1 (16 gload_lds)
  STAGE(gB0, 32768);         STAGE(gB1, 49152);
  STAGE(gA0, 0);             STAGE(gA1, 16384);
  gB0 += 128; gB1 += 128; gA0 += 128; gA1 += 128;
  STAGE(gB0, 65536 + 32768); STAGE(gB1, 65536 + 49152);
  STAGE(gA0, 65536 + 0);     STAGE(gA1, 65536 + 16384);
  gB0 += 128; gB1 += 128; gA0 += 128; gA1 += 128;
  VMCNT(8);        // T0 landed; T1's 8 ops in flight
  S_BARRIER();
  // primer: P=T0 registers for p0's MFMA
  RD_FA4(faL, pAP);          // faL(P): 8 reads
  RD_FB2(fbA, 0, pBP);       // P.fb01 -> fbA: 4 reads

  // ---- main loop: 8 iters x 2 K-tiles; P=2j (buf0), Q=2j+1 (buf1)
  for (int j = 0; j < 8; ++j) {
    const bool full = (j < 7);
    // p0: MFMA P(L,01); load P.fb23->fbB + P.fa45->faH[0:1]
    RD_FB2(fbB, 4096, pBP);
    RD_FA2(faH, 0, 4, pAP);
    S_BARRIER(); SCHED0();
    QMFMA(faL, fbA, 0, 0);
    S_BARRIER();
    // p1: MFMA P(L,23); load P.fa67->faH[2:3]
    RD_FA2(faH, 2, 6, pAP);
    S_BARRIER(); SCHED0();
    QMFMA(faL, fbB, 0, 2);
    S_BARRIER();
    // p2: MFMA P(H,23); stage R.B0,R.B1 -> buf0.B (P.B reg-resident since p1);
    //     vmcnt retires all Q stages -> end barrier publishes for p3's Q reads
    if (full) { STAGE(gB0, 32768); STAGE(gB1, 49152); gB0 += 128; gB1 += 128; }
    S_BARRIER(); SCHED0();
    QMFMA(faH, fbB, 4, 2);
    if (full) { VMCNT(4); } else { VMCNT(0); }
    S_BARRIER();
    // p3: MFMA P(H,01); load Q.faL(8) + Q.fb01->fbB(4); stage R.A0,A1
    RD_FA4(faL, pAQ);
    RD_FB2(fbB, 0, pBQ);
    if (full) { STAGE(gA0, 0); STAGE(gA1, 16384); gA0 += 128; gA1 += 128; }
    S_BARRIER(); SCHED0();
    QMFMA(faH, fbA, 4, 0);
    S_BARRIER();
    // p4: MFMA Q(L,01); load Q.fb23->fbA + Q.fa45
    RD_FB2(fbA, 4096, pBQ);
    RD_FA2(faH, 0, 4, pAQ);
    S_BARRIER(); SCHED0();
    QMFMA(faL, fbB, 0, 0);
    S_BARRIER();
    // p5: MFMA Q(L,23); load Q.fa67
    RD_FA2(faH, 2, 6, pAQ);
    S_BARRIER(); SCHED0();
    QMFMA(faL, fbA, 0, 2);
    S_BARRIER();
    // p6: MFMA Q(H,23); stage S.B0,B1 -> buf1.B; vmcnt retires R for p7 reads
    if (full) { STAGE(gB0, 65536 + 32768); STAGE(gB1, 65536 + 49152);
                gB0 += 128; gB1 += 128; }
    S_BARRIER(); SCHED0();
    QMFMA(faH, fbA, 4, 2);
    if (full) { VMCNT(4); }
    S_BARRIER();
    // p7: MFMA Q(H,01); load R.faL + R.fb01->fbA (next P); stage S.A0,A1
    if (full) {
      RD_FA4(faL, pAP);
      RD_FB2(fbA, 0, pBP);
      STAGE(gA0, 65536 + 0); STAGE(gA1, 65536 + 16384);
      gA0 += 128; gA1 += 128;
    }
    S_BARRIER(); SCHED0();
    QMFMA(faH, fbB, 4, 0);
    S_BARRIER();
  }

  // ---- epilogue: C/D layout col = lane&15, row = (lane>>4)*4 + reg
  const int orow0 = m0 + wm * 128 + (l >> 4) * 4;
  const int ocol = n0 + wn * 64 + ll;
  if constexpr (MODE == 0) {
    const bool isr = (n0 >= 1024);
    bf16* outp = isr ? Rout : Vout;
    const int oc = isr ? (ocol - 1024) : ocol;
    #pragma unroll
    for (int mf = 0; mf < 8; ++mf) {
      #pragma unroll
      for (int i = 0; i < 4; ++i) {
        const size_t ro = (size_t)(orow0 + mf * 16 + i) * 1024 + oc;
        #pragma unroll
        for (int nf = 0; nf < 4; ++nf) {
          float cv = acc[mf][nf][i];
          if (isr) cv = 1.0f / (1.0f + __expf(-cv));
          outp[ro + nf * 16] = __float2bfloat16(cv);
        }
      }
    }
  } else {
    #pragma unroll
    for (int mf = 0; mf < 8; ++mf) {
      #pragma unroll
      for (int i = 0; i < 4; ++i) {
        const size_t ro = (size_t)(orow0 + mf * 16 + i) * 1024 + ocol;
        #pragma unroll
        for (int nf = 0; nf < 4; ++nf) {
          const size_t o = ro + nf * 16;
          Fout[o] = __bfloat162float(Ab[o]) + acc[mf][nf][i];
        }
      }
    }
  }
}

// ---------------- kernel 4: chunk-local decayed sums ----------------
__global__ void scan_partial(const bf16* __restrict__ V, float* __restrict__ sl) {
  const int idx = blockIdx.x * 256 + threadIdx.x;   // 131072 = B*NCHUNK*(D/2)
  const int d2 = idx & 511;
  const int c = (idx >> 9) & 15;
  const int b = idx >> 13;
  const bf162* V2 = (const bf162*)V;
  const size_t base = (size_t)(b * 2048 + c * 128) * 512 + d2;
  float s0 = 0.f, s1 = 0.f;
  for (int w = 0; w < CHUNKL; ++w) {
    const bf162 v = V2[base + (size_t)w * 512];
    s0 = DECAY_F * s0 + OM_F * __bfloat162float(v.x);
    s1 = DECAY_F * s1 + OM_F * __bfloat162float(v.y);
  }
  const int o = (b * 16 + c) * 1024 + d2 * 2;
  sl[o] = s0;
  sl[o + 1] = s1;
}

// ---------------- kernel 5: chunk-level scan ----------------
__global__ void scan_chunk(const float* __restrict__ state,
                           const float* __restrict__ sl,
                           float* __restrict__ sin_,
                           float* __restrict__ state_out,
                           float decayL) {
  const int idx = blockIdx.x * 256 + threadIdx.x;   // 16384 = B*D
  const int d = idx & 1023;
  const int b = idx >> 10;
  float s = state[idx];
  #pragma unroll
  for (int c = 0; c < NCHUNK; ++c) {
    const int o = (b * 16 + c) * 1024 + d;
    sin_[o] = s;
    s = decayL * s + sl[o];
  }
  state_out[idx] = s;
}

// ---------------- kernel 6: y_tmp = xb + r*s (in place over V) ----------
__global__ void scan_apply(const bf16* __restrict__ Xb,
                           const bf16* __restrict__ R,
                           const float* __restrict__ sin_,
                           bf16* __restrict__ VY) {
  const int idx = blockIdx.x * 256 + threadIdx.x;   // 131072
  const int d2 = idx & 511;
  const int c = (idx >> 9) & 15;
  const int b = idx >> 13;
  const bf162* R2 = (const bf162*)R;
  const bf162* X2 = (const bf162*)Xb;
  bf162* VY2 = (bf162*)VY;
  const size_t base = (size_t)(b * 2048 + c * 128) * 512 + d2;
  const int so = (b * 16 + c) * 1024 + d2 * 2;
  float s0 = sin_[so], s1 = sin_[so + 1];
  for (int w = 0; w < CHUNKL; ++w) {
    const size_t off = base + (size_t)w * 512;
    const bf162 v = VY2[off];
    const bf162 r = R2[off];
    const bf162 xx = X2[off];
    s0 = DECAY_F * s0 + OM_F * __bfloat162float(v.x);
    s1 = DECAY_F * s1 + OM_F * __bfloat162float(v.y);
    const float y0 = __bfloat162float(xx.x) + __bfloat162float(r.x) * s0;
    const float y1 = __bfloat162float(xx.y) + __bfloat162float(r.y) * s1;
    bf162 o;
    o.x = __float2bfloat16(y0);
    o.y = __float2bfloat16(y1);
    VY2[off] = o;
  }
}

extern "C" void kernel_launch(void* const* d_in, const int* in_sizes, int n_in,
                              void* d_out, int out_size, void* d_ws, size_t ws_size,
                              hipStream_t stream) {
  const float* x     = (const float*)d_in[0];
  const float* state = (const float*)d_in[1];
  const float* Wv    = (const float*)d_in[2];
  const float* Wr    = (const float*)d_in[3];
  const float* Wc    = (const float*)d_in[4];

  float* y_out = (float*)d_out;
  float* state_out = y_out + (size_t)MROWS * 1024;

  char* ws = (char*)d_ws;
  bf16* WT   = (bf16*)ws;                                    // 6 MiB
  bf16* Xb   = (bf16*)(ws + ((size_t)6 << 20));              // 64 MiB
  bf16* Vbuf = (bf16*)(ws + ((size_t)70 << 20));             // 64 MiB (also y_tmp)
  bf16* Rbuf = (bf16*)(ws + ((size_t)134 << 20));            // 64 MiB
  float* sl  = (float*)(ws + ((size_t)198 << 20));           // 1 MiB
  float* sin_ = (float*)(ws + ((size_t)199 << 20));          // 1 MiB
  bf16* WcT = WT + (size_t)2048 * 1024;

  const float decayL = (float)pow(0.99, (double)CHUNKL);

  // one-time: allow 128 KiB dynamic LDS (host-side config, not a stream op)
  static bool g_cfg = false;
  if (!g_cfg) {
    auto kf0 = gemm8<0>;
    auto kf1 = gemm8<1>;
    (void)hipFuncSetAttribute((const void*)kf0,
                              hipFuncAttributeMaxDynamicSharedMemorySize, 131072);
    (void)hipFuncSetAttribute((const void*)kf1,
                              hipFuncAttributeMaxDynamicSharedMemorySize, 131072);
    g_cfg = true;
  }

  prep_x<<<32768, 256, 0, stream>>>(x, Xb);
  prep_weights<<<dim3(32, 96), dim3(32, 8), 0, stream>>>(Wv, Wr, Wc, WT);
  gemm8<0><<<1024, 512, 131072, stream>>>(Xb, WT, Vbuf, Rbuf, nullptr);
  scan_partial<<<512, 256, 0, stream>>>(Vbuf, sl);
  scan_chunk<<<64, 256, 0, stream>>>(state, sl, sin_, state_out, decayL);
  scan_apply<<<512, 256, 0, stream>>>(Xb, Rbuf, sin_, Vbuf);
  gemm8<1><<<512, 512, 131072, stream>>>(Vbuf, WcT, nullptr, nullptr, y_out);
}